// Round 1
// 777.693 us; speedup vs baseline: 1.0740x; 1.0740x over previous
//
#include <hip/hip_runtime.h>

#define BN_EPS 1e-5f

using f4 = __attribute__((ext_vector_type(4))) float;

__device__ inline f4 relu4(f4 v) {
    v.x = fmaxf(v.x, 0.f); v.y = fmaxf(v.y, 0.f);
    v.z = fmaxf(v.z, 0.f); v.w = fmaxf(v.w, 0.f);
    return v;
}

// ---------------------------------------------------------------------------
// Edge-index canonicalization: harness may hand us int32 or raw int64 data.
// If int64 (little-endian, values < 2^31), every odd int32 word is 0.
// ---------------------------------------------------------------------------
__global__ __launch_bounds__(256) void detect_i64_kernel(const int* __restrict__ ei,
                                                         int* __restrict__ flag, int npairs) {
    __shared__ int ok;
    if (threadIdx.x == 0) ok = 1;
    __syncthreads();
    bool bad = false;
    for (int i = threadIdx.x; i < npairs; i += 256)
        bad |= (ei[2 * i + 1] != 0);
    if (bad) ok = 0;
    __syncthreads();
    if (threadIdx.x == 0) *flag = ok;
}

// canon + zero-deg fused (canon grid covers max(2E, N))
__global__ __launch_bounds__(256) void canon_kernel(const int* __restrict__ ei,
                                                    const int* __restrict__ flag,
                                                    int* __restrict__ canon,
                                                    int* __restrict__ deg, int n2, int N) {
    int i = blockIdx.x * 256 + threadIdx.x;
    if (i < N) deg[i] = 0;
    if (i >= n2) return;
    int wide = *flag;
    canon[i] = wide ? ei[2 * i] : ei[i];
}

__global__ __launch_bounds__(256) void hist_kernel(const int* __restrict__ dst,
                                                   int* __restrict__ deg, int E) {
    int e = blockIdx.x * 256 + threadIdx.x;
    if (e >= E) return;
    atomicAdd(&deg[dst[e]], 1);
}

// Single-block exclusive prefix scan over deg[N] -> rowptr[N+1], cursor[N]
__global__ __launch_bounds__(1024) void scan_kernel(const int* __restrict__ deg,
                                                    int* __restrict__ rowptr,
                                                    int* __restrict__ cursor, int N) {
    __shared__ int part[1024];
    int t = threadIdx.x;
    int chunk = (N + 1023) / 1024;
    int lo = t * chunk;
    int hi = lo + chunk;
    if (lo > N) lo = N;
    if (hi > N) hi = N;
    int s = 0;
    for (int i = lo; i < hi; ++i) s += deg[i];
    part[t] = s;
    __syncthreads();
    for (int off = 1; off < 1024; off <<= 1) {
        int v = (t >= off) ? part[t - off] : 0;
        __syncthreads();
        part[t] += v;
        __syncthreads();
    }
    int run = (t == 0) ? 0 : part[t - 1];
    for (int i = lo; i < hi; ++i) { rowptr[i] = run; cursor[i] = run; run += deg[i]; }
    if (t == 1023) rowptr[N] = run;
}

// Scatter (edge id, src id) pairs into dst-ordered buckets
__global__ __launch_bounds__(256) void fill_kernel(const int* __restrict__ src,
                                                   const int* __restrict__ dst,
                                                   int* __restrict__ cursor,
                                                   int2* __restrict__ pbuf, int E) {
    int e = blockIdx.x * 256 + threadIdx.x;
    if (e >= E) return;
    int d = dst[e];
    int pos = atomicAdd(&cursor[d], 1);
    pbuf[pos] = make_int2(e, src[e]);
}

// ---------------------------------------------------------------------------
// Gather-reduce: aggx[n] = x[n] + sum_{e in bucket(n)} relu(x[src_e] + ea[e])
// 32 lanes per node; lane f owns float4 column f. 2-edge unroll for MLP.
// ea is streamed nontemporally (zero reuse) to keep x resident in L2.
// Block 0 also zeroes the 256-float stats buffer for the following gemm<1>.
// ---------------------------------------------------------------------------
__global__ __launch_bounds__(256) void gather_kernel(const float* __restrict__ x,
                                                     const float* __restrict__ ea,
                                                     const int* __restrict__ rowptr,
                                                     const int2* __restrict__ pbuf,
                                                     float* __restrict__ aggx,
                                                     float* __restrict__ sums, int N) {
    if (blockIdx.x == 0) sums[threadIdx.x] = 0.f;
    int t = blockIdx.x * 256 + threadIdx.x;
    int n = t >> 5;
    if (n >= N) return;
    int f = t & 31;
    int lo = rowptr[n], hi = rowptr[n + 1];
    f4 acc0 = ((const f4*)(x + (size_t)n * 128))[f];   // self row (eps=0 residual)
    f4 acc1 = {0.f, 0.f, 0.f, 0.f};
    int i = lo;
    for (; i + 2 <= hi; i += 2) {
        int2 p0 = pbuf[i];
        int2 p1 = pbuf[i + 1];
        f4 xv0 = ((const f4*)(x + (size_t)p0.y * 128))[f];
        f4 av0 = __builtin_nontemporal_load(((const f4*)(ea + (size_t)p0.x * 128)) + f);
        f4 xv1 = ((const f4*)(x + (size_t)p1.y * 128))[f];
        f4 av1 = __builtin_nontemporal_load(((const f4*)(ea + (size_t)p1.x * 128)) + f);
        acc0 += relu4(xv0 + av0);
        acc1 += relu4(xv1 + av1);
    }
    if (i < hi) {
        int2 p0 = pbuf[i];
        f4 xv0 = ((const f4*)(x + (size_t)p0.y * 128))[f];
        f4 av0 = __builtin_nontemporal_load(((const f4*)(ea + (size_t)p0.x * 128)) + f);
        acc0 += relu4(xv0 + av0);
    }
    f4 r = acc0 + acc1;
    ((f4*)(aggx + (size_t)n * 128))[f] = r;
}

// ---------------------------------------------------------------------------
// GEMM  (M x 128) @ (128 x 128) + bias.
// MODE 1: A = aggx,                   out = acc + b   (pre-BN h)
//         + fused column sum/sumsq of h -> sums[0:128], sums[128:256] (atomics)
// MODE 2: A = relu(h*scale + shift),  out = relu(acc + b)
//         scale/shift derived per-block from sums/gamma/beta in prologue.
// Column split per thread: {4cg..4cg+3} and {64+4cg..64+4cg+3} so both sW
// b128 reads are lane-consecutive (conflict-free; old 8cg split was 4-way).
// ---------------------------------------------------------------------------
template <int MODE>
__global__ __launch_bounds__(256) void gemm_kernel(const float* __restrict__ A,
                                                   const float* __restrict__ W,
                                                   const float* __restrict__ bias,
                                                   float* __restrict__ sums,
                                                   const float* __restrict__ gamma,
                                                   const float* __restrict__ beta,
                                                   float* __restrict__ out, int N,
                                                   float invN) {
    __shared__ float sA[64][132];
    __shared__ float sW[32][128];
    __shared__ float sScale[128];
    __shared__ float sShift[128];
    int t = threadIdx.x;
    int rbase = blockIdx.x * 64;

    if (MODE == 2) {
        if (t < 128) {
            float mean = sums[t] * invN;
            float var = sums[128 + t] * invN - mean * mean;
            float inv = rsqrtf(var + BN_EPS);
            float sc = gamma[t] * inv;
            sScale[t] = sc;
            sShift[t] = beta[t] - mean * sc;
        }
        __syncthreads();
    }

    {
        int colq = t & 31;
        int r0 = t >> 5;
        float4 s4 = make_float4(0.f, 0.f, 0.f, 0.f), sh4 = make_float4(0.f, 0.f, 0.f, 0.f);
        if (MODE == 2) {
            s4 = reinterpret_cast<const float4*>(sScale)[colq];
            sh4 = reinterpret_cast<const float4*>(sShift)[colq];
        }
#pragma unroll
        for (int it = 0; it < 8; ++it) {
            int r = r0 + it * 8;
            int row = rbase + r;
            float4 v = make_float4(0.f, 0.f, 0.f, 0.f);
            if (row < N) {
                float4 a = reinterpret_cast<const float4*>(A + (size_t)row * 128)[colq];
                if (MODE == 1) {
                    v = a;
                } else {
                    v.x = fmaxf(a.x * s4.x + sh4.x, 0.f);
                    v.y = fmaxf(a.y * s4.y + sh4.y, 0.f);
                    v.z = fmaxf(a.z * s4.z + sh4.z, 0.f);
                    v.w = fmaxf(a.w * s4.w + sh4.w, 0.f);
                }
            }
            *reinterpret_cast<float4*>(&sA[r][colq * 4]) = v;
        }
    }

    float acc[4][8];
#pragma unroll
    for (int r = 0; r < 4; ++r)
#pragma unroll
        for (int c = 0; c < 8; ++c) acc[r][c] = 0.f;

    int cg = t & 15, rg = t >> 4;
    int c0a = cg * 4;
    int c0b = 64 + cg * 4;

    for (int kc = 0; kc < 4; ++kc) {
        __syncthreads();
#pragma unroll
        for (int pass = 0; pass < 4; ++pass) {
            int kk = (t >> 5) + pass * 8;
            int k = kc * 32 + kk;
            float4 w = reinterpret_cast<const float4*>(W + (size_t)k * 128)[t & 31];
            *reinterpret_cast<float4*>(&sW[kk][(t & 31) * 4]) = w;
        }
        __syncthreads();
#pragma unroll
        for (int kk0 = 0; kk0 < 32; kk0 += 4) {
            float4 a[4];
#pragma unroll
            for (int r = 0; r < 4; ++r)
                a[r] = *reinterpret_cast<const float4*>(&sA[rg * 4 + r][kc * 32 + kk0]);
#pragma unroll
            for (int j = 0; j < 4; ++j) {
                float4 w0 = *reinterpret_cast<const float4*>(&sW[kk0 + j][c0a]);
                float4 w1 = *reinterpret_cast<const float4*>(&sW[kk0 + j][c0b]);
#pragma unroll
                for (int r = 0; r < 4; ++r) {
                    float av = (j == 0) ? a[r].x : (j == 1) ? a[r].y : (j == 2) ? a[r].z : a[r].w;
                    acc[r][0] += av * w0.x;
                    acc[r][1] += av * w0.y;
                    acc[r][2] += av * w0.z;
                    acc[r][3] += av * w0.w;
                    acc[r][4] += av * w1.x;
                    acc[r][5] += av * w1.y;
                    acc[r][6] += av * w1.z;
                    acc[r][7] += av * w1.w;
                }
            }
        }
    }

    float4 b0 = *reinterpret_cast<const float4*>(bias + c0a);
    float4 b1v = *reinterpret_cast<const float4*>(bias + c0b);
    float cs[8], cs2[8];
#pragma unroll
    for (int j = 0; j < 8; ++j) { cs[j] = 0.f; cs2[j] = 0.f; }

#pragma unroll
    for (int r = 0; r < 4; ++r) {
        int row = rbase + rg * 4 + r;
        if (row >= N) continue;
        float4 o0, o1;
        o0.x = acc[r][0] + b0.x;  o0.y = acc[r][1] + b0.y;
        o0.z = acc[r][2] + b0.z;  o0.w = acc[r][3] + b0.w;
        o1.x = acc[r][4] + b1v.x; o1.y = acc[r][5] + b1v.y;
        o1.z = acc[r][6] + b1v.z; o1.w = acc[r][7] + b1v.w;
        if (MODE == 2) {
            o0.x = fmaxf(o0.x, 0.f); o0.y = fmaxf(o0.y, 0.f);
            o0.z = fmaxf(o0.z, 0.f); o0.w = fmaxf(o0.w, 0.f);
            o1.x = fmaxf(o1.x, 0.f); o1.y = fmaxf(o1.y, 0.f);
            o1.z = fmaxf(o1.z, 0.f); o1.w = fmaxf(o1.w, 0.f);
        } else {
            cs[0] += o0.x; cs2[0] += o0.x * o0.x;
            cs[1] += o0.y; cs2[1] += o0.y * o0.y;
            cs[2] += o0.z; cs2[2] += o0.z * o0.z;
            cs[3] += o0.w; cs2[3] += o0.w * o0.w;
            cs[4] += o1.x; cs2[4] += o1.x * o1.x;
            cs[5] += o1.y; cs2[5] += o1.y * o1.y;
            cs[6] += o1.z; cs2[6] += o1.z * o1.z;
            cs[7] += o1.w; cs2[7] += o1.w * o1.w;
        }
        *reinterpret_cast<float4*>(out + (size_t)row * 128 + c0a) = o0;
        *reinterpret_cast<float4*>(out + (size_t)row * 128 + c0b) = o1;
    }

    if (MODE == 1) {
        // block-level column reduction of cs/cs2 via sA scratch, then 1 atomic/col
        __syncthreads();  // everyone done reading sA
        float* red = &sA[0][0];
        float* red2 = red + 2048;
        int base = (rg * 16 + cg) * 8;
#pragma unroll
        for (int j = 0; j < 8; ++j) { red[base + j] = cs[j]; red2[base + j] = cs2[j]; }
        __syncthreads();
        if (t < 128) {
            int cgj = (t & 63) >> 2;
            int j = (t & 3) + ((t >> 6) << 2);
            float s = 0.f, s2 = 0.f;
#pragma unroll
            for (int rr = 0; rr < 16; ++rr) {
                s += red[(rr * 16 + cgj) * 8 + j];
                s2 += red2[(rr * 16 + cgj) * 8 + j];
            }
            unsafeAtomicAdd(&sums[t], s);
            unsafeAtomicAdd(&sums[128 + t], s2);
        }
    }
}

// ---------------------------------------------------------------------------
extern "C" void kernel_launch(void* const* d_in, const int* in_sizes, int n_in,
                              void* d_out, int out_size, void* d_ws, size_t ws_size,
                              hipStream_t stream) {
    const float* x     = (const float*)d_in[0];
    const int*   ei    = (const int*)d_in[1];
    const float* ea    = (const float*)d_in[2];
    const float* W1    = (const float*)d_in[3];
    const float* b1    = (const float*)d_in[4];
    const float* gamma = (const float*)d_in[5];
    const float* beta  = (const float*)d_in[6];
    const float* W2    = (const float*)d_in[7];
    const float* b2    = (const float*)d_in[8];

    int N = in_sizes[0] / 128;
    int E = in_sizes[2] / 128;
    int L = in_sizes[3] / (128 * 128);

    size_t NF = (size_t)N * 128;
    float* aggx  = (float*)d_ws;
    float* h     = aggx + NF;
    float* sums  = h + NF;               // 256 floats: sum[128] | sumsq[128]
    int*   canon  = (int*)(sums + 256);
    int*   deg    = canon + (size_t)2 * E;
    int*   rowptr = deg + N;             // N+2 slots (parity pad for pbuf align)
    int*   cursor = rowptr + N + 2;
    int2*  pbuf   = (int2*)(cursor + N); // E pairs (ebuf/sbuf interleaved)
    int*   flag   = (int*)(pbuf + E);

    // ---- Canonicalize edge indices (int64-vs-int32 marshalling safety) ----
    int npairs = (E < 4096) ? E : 4096;
    detect_i64_kernel<<<1, 256, 0, stream>>>(ei, flag, npairs);
    int E2 = 2 * E;
    int m = (E2 > N) ? E2 : N;
    canon_kernel<<<(m + 255) / 256, 256, 0, stream>>>(ei, flag, canon, deg, E2, N);
    const int* src = canon;
    const int* dst = canon + E;

    // ---- Build CSR over dst (once; topology is layer-invariant) ----
    int eBlocks = (E + 255) / 256;
    hist_kernel<<<eBlocks, 256, 0, stream>>>(dst, deg, E);
    scan_kernel<<<1, 1024, 0, stream>>>(deg, rowptr, cursor, N);
    fill_kernel<<<eBlocks, 256, 0, stream>>>(src, dst, cursor, pbuf, E);

    // ---- Layers ----
    int gatherBlocks = (N * 32 + 255) / 256;
    int gemmBlocks = (N + 63) / 64;
    float invN = 1.0f / (float)N;
    const float* xin = x;
    for (int l = 0; l < L; ++l) {
        float* xout = (float*)d_out;  // layer0 intermediate lives in d_out, overwritten by layer1
        gather_kernel<<<gatherBlocks, 256, 0, stream>>>(xin, ea, rowptr, pbuf, aggx, sums, N);
        gemm_kernel<1><<<gemmBlocks, 256, 0, stream>>>(aggx, W1 + (size_t)l * 16384,
                                                       b1 + (size_t)l * 128, sums,
                                                       nullptr, nullptr, h, N, invN);
        gemm_kernel<2><<<gemmBlocks, 256, 0, stream>>>(h, W2 + (size_t)l * 16384,
                                                       b2 + (size_t)l * 128, sums,
                                                       gamma + (size_t)l * 128,
                                                       beta + (size_t)l * 128, xout, N, invN);
        xin = xout;
    }
}

// Round 3
// 677.252 us; speedup vs baseline: 1.2333x; 1.1483x over previous
//
#include <hip/hip_runtime.h>

#define BN_EPS 1e-5f

using f4 = __attribute__((ext_vector_type(4))) float;

__device__ inline f4 relu4(f4 v) {
    v.x = fmaxf(v.x, 0.f); v.y = fmaxf(v.y, 0.f);
    v.z = fmaxf(v.z, 0.f); v.w = fmaxf(v.w, 0.f);
    return v;
}

// ---------------------------------------------------------------------------
// detect int64-vs-int32 edge marshalling; also zeroes deg[N] (gates canon+hist)
// ---------------------------------------------------------------------------
__global__ __launch_bounds__(256) void detect_i64_kernel(const int* __restrict__ ei,
                                                         int* __restrict__ flag, int npairs,
                                                         int* __restrict__ deg, int N) {
    __shared__ int ok;
    if (threadIdx.x == 0) ok = 1;
    __syncthreads();
    bool bad = false;
    for (int i = threadIdx.x; i < npairs; i += 256)
        bad |= (ei[2 * i + 1] != 0);
    if (bad) ok = 0;
    // zero the degree array (256 threads, vectorized)
    int nq = N >> 2;
    int4* d4 = (int4*)deg;
    for (int i = threadIdx.x; i < nq; i += 256) d4[i] = make_int4(0, 0, 0, 0);
    for (int i = (nq << 2) + threadIdx.x; i < N; i += 256) deg[i] = 0;
    __syncthreads();
    if (threadIdx.x == 0) *flag = ok;
}

// canon + fused degree histogram (dst entries live in canon[E..2E))
__global__ __launch_bounds__(256) void canon_kernel(const int* __restrict__ ei,
                                                    const int* __restrict__ flag,
                                                    int* __restrict__ canon,
                                                    int* __restrict__ deg, int n2, int E) {
    int i = blockIdx.x * 256 + threadIdx.x;
    if (i >= n2) return;
    int wide = *flag;
    int v = wide ? ei[2 * i] : ei[i];
    canon[i] = v;
    if (i >= E) atomicAdd(&deg[v], 1);
}

// ---------------------------------------------------------------------------
// 3-stage parallel exclusive scan: deg[N] -> rowptr[N+1], cursor[N]
// ---------------------------------------------------------------------------
__global__ __launch_bounds__(256) void scan_blk_kernel(const int* __restrict__ deg,
                                                       int* __restrict__ rowptr,
                                                       int* __restrict__ partials, int N) {
    __shared__ int s[256];
    int b = blockIdx.x, t = threadIdx.x;
    int base = b * 1024 + t * 4;
    int4 v = make_int4(0, 0, 0, 0);
    if (base + 3 < N) v = *(const int4*)(deg + base);
    else {
        if (base < N) v.x = deg[base];
        if (base + 1 < N) v.y = deg[base + 1];
        if (base + 2 < N) v.z = deg[base + 2];
        if (base + 3 < N) v.w = deg[base + 3];
    }
    s[t] = v.x + v.y + v.z + v.w;
    __syncthreads();
    for (int off = 1; off < 256; off <<= 1) {
        int u = (t >= off) ? s[t - off] : 0;
        __syncthreads();
        s[t] += u;
        __syncthreads();
    }
    int excl = (t == 0) ? 0 : s[t - 1];
    int4 w;
    w.x = excl;
    w.y = excl + v.x;
    w.z = w.y + v.y;
    w.w = w.z + v.z;
    if (base + 3 < N) *(int4*)(rowptr + base) = w;
    else {
        if (base < N) rowptr[base] = w.x;
        if (base + 1 < N) rowptr[base + 1] = w.y;
        if (base + 2 < N) rowptr[base + 2] = w.z;
        if (base + 3 < N) rowptr[base + 3] = w.w;
    }
    if (t == 255) partials[b] = s[255];
}

__global__ __launch_bounds__(256) void scan_part_kernel(int* __restrict__ partials, int nb) {
    __shared__ int s[256];
    int t = threadIdx.x;
    if (nb <= 256) {
        s[t] = (t < nb) ? partials[t] : 0;
        __syncthreads();
        for (int off = 1; off < 256; off <<= 1) {
            int u = (t >= off) ? s[t - off] : 0;
            __syncthreads();
            s[t] += u;
            __syncthreads();
        }
        if (t < nb) partials[t] = (t == 0) ? 0 : s[t - 1];
    } else if (t == 0) {  // generic fallback
        int run = 0;
        for (int i = 0; i < nb; ++i) { int d = partials[i]; partials[i] = run; run += d; }
    }
}

__global__ __launch_bounds__(256) void scan_add_kernel(int* __restrict__ rowptr,
                                                       int* __restrict__ cursor,
                                                       const int* __restrict__ partials,
                                                       int N, int E) {
    int i = blockIdx.x * 256 + threadIdx.x;
    if (i < N) {
        int v = rowptr[i] + partials[i >> 10];
        rowptr[i] = v;
        cursor[i] = v;
    }
    if (i == N) rowptr[N] = E;
}

// Scatter (edge id, src id) pairs into dst-ordered buckets
__global__ __launch_bounds__(256) void fill_kernel(const int* __restrict__ src,
                                                   const int* __restrict__ dst,
                                                   int* __restrict__ cursor,
                                                   int2* __restrict__ pbuf, int E) {
    int e = blockIdx.x * 256 + threadIdx.x;
    if (e >= E) return;
    int d = dst[e];
    int pos = atomicAdd(&cursor[d], 1);
    pbuf[pos] = make_int2(e, src[e]);
}

// ---------------------------------------------------------------------------
// Gather-reduce: aggx[n] = x[n] + sum_{e in bucket(n)} relu(x[src_e] + ea[e])
// 32 lanes per node; lane f owns float4 column f. 4-edge unroll: 4 pbuf pairs
// + 8 row loads in flight per group to cover L3/HBM latency.
// ea is streamed nontemporally (zero reuse) to keep x resident in L2.
// Block 0 also zeroes the 256-float stats buffer for the following gemm<1>.
// ---------------------------------------------------------------------------
__global__ __launch_bounds__(256) void gather_kernel(const float* __restrict__ x,
                                                     const float* __restrict__ ea,
                                                     const int* __restrict__ rowptr,
                                                     const int2* __restrict__ pbuf,
                                                     float* __restrict__ aggx,
                                                     float* __restrict__ sums, int N) {
    if (blockIdx.x == 0) sums[threadIdx.x] = 0.f;
    int t = blockIdx.x * 256 + threadIdx.x;
    int n = t >> 5;
    if (n >= N) return;
    int f = t & 31;
    int lo = rowptr[n], hi = rowptr[n + 1];
    f4 acc0 = ((const f4*)(x + (size_t)n * 128))[f];  // self row (eps=0 residual)
    f4 acc1 = {0.f, 0.f, 0.f, 0.f};
    f4 acc2 = {0.f, 0.f, 0.f, 0.f};
    f4 acc3 = {0.f, 0.f, 0.f, 0.f};
    int i = lo;
    for (; i + 4 <= hi; i += 4) {
        int2 q0 = pbuf[i];
        int2 q1 = pbuf[i + 1];
        int2 q2 = pbuf[i + 2];
        int2 q3 = pbuf[i + 3];
        f4 xa = ((const f4*)(x + (size_t)q0.y * 128))[f];
        f4 aa = __builtin_nontemporal_load(((const f4*)(ea + (size_t)q0.x * 128)) + f);
        f4 xb = ((const f4*)(x + (size_t)q1.y * 128))[f];
        f4 ab = __builtin_nontemporal_load(((const f4*)(ea + (size_t)q1.x * 128)) + f);
        f4 xc = ((const f4*)(x + (size_t)q2.y * 128))[f];
        f4 ac = __builtin_nontemporal_load(((const f4*)(ea + (size_t)q2.x * 128)) + f);
        f4 xd = ((const f4*)(x + (size_t)q3.y * 128))[f];
        f4 ad = __builtin_nontemporal_load(((const f4*)(ea + (size_t)q3.x * 128)) + f);
        acc0 += relu4(xa + aa);
        acc1 += relu4(xb + ab);
        acc2 += relu4(xc + ac);
        acc3 += relu4(xd + ad);
    }
    for (; i + 2 <= hi; i += 2) {
        int2 q0 = pbuf[i];
        int2 q1 = pbuf[i + 1];
        f4 xa = ((const f4*)(x + (size_t)q0.y * 128))[f];
        f4 aa = __builtin_nontemporal_load(((const f4*)(ea + (size_t)q0.x * 128)) + f);
        f4 xb = ((const f4*)(x + (size_t)q1.y * 128))[f];
        f4 ab = __builtin_nontemporal_load(((const f4*)(ea + (size_t)q1.x * 128)) + f);
        acc0 += relu4(xa + aa);
        acc1 += relu4(xb + ab);
    }
    if (i < hi) {
        int2 q0 = pbuf[i];
        f4 xa = ((const f4*)(x + (size_t)q0.y * 128))[f];
        f4 aa = __builtin_nontemporal_load(((const f4*)(ea + (size_t)q0.x * 128)) + f);
        acc0 += relu4(xa + aa);
    }
    f4 r = (acc0 + acc1) + (acc2 + acc3);
    ((f4*)(aggx + (size_t)n * 128))[f] = r;
}

// ---------------------------------------------------------------------------
// GEMM  (M x 128) @ (128 x 128) + bias.
// MODE 1: A = aggx,                   out = acc + b   (pre-BN h)
//         + fused column sum/sumsq of h -> sums[0:128], sums[128:256] (atomics)
// MODE 2: A = relu(h*scale + shift),  out = relu(acc + b)
//         scale/shift derived per-block from sums/gamma/beta in prologue.
// Column split per thread: {4cg..4cg+3} and {64+4cg..64+4cg+3} so both sW
// b128 reads are lane-consecutive (conflict-free).
// ---------------------------------------------------------------------------
template <int MODE>
__global__ __launch_bounds__(256) void gemm_kernel(const float* __restrict__ A,
                                                   const float* __restrict__ W,
                                                   const float* __restrict__ bias,
                                                   float* __restrict__ sums,
                                                   const float* __restrict__ gamma,
                                                   const float* __restrict__ beta,
                                                   float* __restrict__ out, int N,
                                                   float invN) {
    __shared__ float sA[64][132];
    __shared__ float sW[32][128];
    __shared__ float sScale[128];
    __shared__ float sShift[128];
    int t = threadIdx.x;
    int rbase = blockIdx.x * 64;

    if (MODE == 2) {
        if (t < 128) {
            float mean = sums[t] * invN;
            float var = sums[128 + t] * invN - mean * mean;
            float inv = rsqrtf(var + BN_EPS);
            float sc = gamma[t] * inv;
            sScale[t] = sc;
            sShift[t] = beta[t] - mean * sc;
        }
        __syncthreads();
    }

    {
        int colq = t & 31;
        int r0 = t >> 5;
        float4 s4 = make_float4(0.f, 0.f, 0.f, 0.f), sh4 = make_float4(0.f, 0.f, 0.f, 0.f);
        if (MODE == 2) {
            s4 = reinterpret_cast<const float4*>(sScale)[colq];
            sh4 = reinterpret_cast<const float4*>(sShift)[colq];
        }
#pragma unroll
        for (int it = 0; it < 8; ++it) {
            int r = r0 + it * 8;
            int row = rbase + r;
            float4 v = make_float4(0.f, 0.f, 0.f, 0.f);
            if (row < N) {
                float4 a = reinterpret_cast<const float4*>(A + (size_t)row * 128)[colq];
                if (MODE == 1) {
                    v = a;
                } else {
                    v.x = fmaxf(a.x * s4.x + sh4.x, 0.f);
                    v.y = fmaxf(a.y * s4.y + sh4.y, 0.f);
                    v.z = fmaxf(a.z * s4.z + sh4.z, 0.f);
                    v.w = fmaxf(a.w * s4.w + sh4.w, 0.f);
                }
            }
            *reinterpret_cast<float4*>(&sA[r][colq * 4]) = v;
        }
    }

    float acc[4][8];
#pragma unroll
    for (int r = 0; r < 4; ++r)
#pragma unroll
        for (int c = 0; c < 8; ++c) acc[r][c] = 0.f;

    int cg = t & 15, rg = t >> 4;
    int c0a = cg * 4;
    int c0b = 64 + cg * 4;

    for (int kc = 0; kc < 4; ++kc) {
        __syncthreads();
#pragma unroll
        for (int pass = 0; pass < 4; ++pass) {
            int kk = (t >> 5) + pass * 8;
            int k = kc * 32 + kk;
            float4 w = reinterpret_cast<const float4*>(W + (size_t)k * 128)[t & 31];
            *reinterpret_cast<float4*>(&sW[kk][(t & 31) * 4]) = w;
        }
        __syncthreads();
#pragma unroll
        for (int kk0 = 0; kk0 < 32; kk0 += 4) {
            float4 a[4];
#pragma unroll
            for (int r = 0; r < 4; ++r)
                a[r] = *reinterpret_cast<const float4*>(&sA[rg * 4 + r][kc * 32 + kk0]);
#pragma unroll
            for (int j = 0; j < 4; ++j) {
                float4 w0 = *reinterpret_cast<const float4*>(&sW[kk0 + j][c0a]);
                float4 w1 = *reinterpret_cast<const float4*>(&sW[kk0 + j][c0b]);
#pragma unroll
                for (int r = 0; r < 4; ++r) {
                    float av = (j == 0) ? a[r].x : (j == 1) ? a[r].y : (j == 2) ? a[r].z : a[r].w;
                    acc[r][0] += av * w0.x;
                    acc[r][1] += av * w0.y;
                    acc[r][2] += av * w0.z;
                    acc[r][3] += av * w0.w;
                    acc[r][4] += av * w1.x;
                    acc[r][5] += av * w1.y;
                    acc[r][6] += av * w1.z;
                    acc[r][7] += av * w1.w;
                }
            }
        }
    }

    float4 b0 = *reinterpret_cast<const float4*>(bias + c0a);
    float4 b1v = *reinterpret_cast<const float4*>(bias + c0b);
    float cs[8], cs2[8];
#pragma unroll
    for (int j = 0; j < 8; ++j) { cs[j] = 0.f; cs2[j] = 0.f; }

#pragma unroll
    for (int r = 0; r < 4; ++r) {
        int row = rbase + rg * 4 + r;
        if (row >= N) continue;
        float4 o0, o1;
        o0.x = acc[r][0] + b0.x;  o0.y = acc[r][1] + b0.y;
        o0.z = acc[r][2] + b0.z;  o0.w = acc[r][3] + b0.w;
        o1.x = acc[r][4] + b1v.x; o1.y = acc[r][5] + b1v.y;
        o1.z = acc[r][6] + b1v.z; o1.w = acc[r][7] + b1v.w;
        if (MODE == 2) {
            o0.x = fmaxf(o0.x, 0.f); o0.y = fmaxf(o0.y, 0.f);
            o0.z = fmaxf(o0.z, 0.f); o0.w = fmaxf(o0.w, 0.f);
            o1.x = fmaxf(o1.x, 0.f); o1.y = fmaxf(o1.y, 0.f);
            o1.z = fmaxf(o1.z, 0.f); o1.w = fmaxf(o1.w, 0.f);
        } else {
            cs[0] += o0.x; cs2[0] += o0.x * o0.x;
            cs[1] += o0.y; cs2[1] += o0.y * o0.y;
            cs[2] += o0.z; cs2[2] += o0.z * o0.z;
            cs[3] += o0.w; cs2[3] += o0.w * o0.w;
            cs[4] += o1.x; cs2[4] += o1.x * o1.x;
            cs[5] += o1.y; cs2[5] += o1.y * o1.y;
            cs[6] += o1.z; cs2[6] += o1.z * o1.z;
            cs[7] += o1.w; cs2[7] += o1.w * o1.w;
        }
        *reinterpret_cast<float4*>(out + (size_t)row * 128 + c0a) = o0;
        *reinterpret_cast<float4*>(out + (size_t)row * 128 + c0b) = o1;
    }

    if (MODE == 1) {
        // block-level column reduction of cs/cs2 via sA scratch, then 1 atomic/col
        __syncthreads();  // everyone done reading sA
        float* red = &sA[0][0];
        float* red2 = red + 2048;
        int base = (rg * 16 + cg) * 8;
#pragma unroll
        for (int j = 0; j < 8; ++j) { red[base + j] = cs[j]; red2[base + j] = cs2[j]; }
        __syncthreads();
        if (t < 128) {
            int cgj = (t & 63) >> 2;
            int j = (t & 3) + ((t >> 6) << 2);
            float s = 0.f, s2 = 0.f;
#pragma unroll
            for (int rr = 0; rr < 16; ++rr) {
                s += red[(rr * 16 + cgj) * 8 + j];
                s2 += red2[(rr * 16 + cgj) * 8 + j];
            }
            unsafeAtomicAdd(&sums[t], s);
            unsafeAtomicAdd(&sums[128 + t], s2);
        }
    }
}

// ---------------------------------------------------------------------------
extern "C" void kernel_launch(void* const* d_in, const int* in_sizes, int n_in,
                              void* d_out, int out_size, void* d_ws, size_t ws_size,
                              hipStream_t stream) {
    const float* x     = (const float*)d_in[0];
    const int*   ei    = (const int*)d_in[1];
    const float* ea    = (const float*)d_in[2];
    const float* W1    = (const float*)d_in[3];
    const float* b1    = (const float*)d_in[4];
    const float* gamma = (const float*)d_in[5];
    const float* beta  = (const float*)d_in[6];
    const float* W2    = (const float*)d_in[7];
    const float* b2    = (const float*)d_in[8];

    int N = in_sizes[0] / 128;
    int E = in_sizes[2] / 128;
    int L = in_sizes[3] / (128 * 128);

    size_t NF = (size_t)N * 128;
    float* aggx  = (float*)d_ws;
    float* h     = aggx + NF;
    float* sums  = h + NF;               // 256 floats: sum[128] | sumsq[128]
    int*   canon  = (int*)(sums + 256);
    int*   deg    = canon + (size_t)2 * E;
    int*   rowptr = deg + N;             // N+2 slots (parity pad for pbuf align)
    int*   cursor = rowptr + N + 2;
    int2*  pbuf   = (int2*)(cursor + N); // E pairs (ebuf/sbuf interleaved)
    int*   partials = (int*)(pbuf + E);  // ceil(N/1024) block partials
    int*   flag   = partials + ((N + 1023) / 1024) + 1;

    // ---- Canonicalize edges + degree histogram (int64 marshalling safety) ----
    int npairs = (E < 4096) ? E : 4096;
    detect_i64_kernel<<<1, 256, 0, stream>>>(ei, flag, npairs, deg, N);
    int E2 = 2 * E;
    canon_kernel<<<(E2 + 255) / 256, 256, 0, stream>>>(ei, flag, canon, deg, E2, E);
    const int* src = canon;
    const int* dst = canon + E;

    // ---- Parallel 3-stage scan + CSR fill (once; topology layer-invariant) ----
    int nb = (N + 1023) / 1024;
    scan_blk_kernel<<<nb, 256, 0, stream>>>(deg, rowptr, partials, N);
    scan_part_kernel<<<1, 256, 0, stream>>>(partials, nb);
    scan_add_kernel<<<(N + 256) / 256, 256, 0, stream>>>(rowptr, cursor, partials, N, E);
    int eBlocks = (E + 255) / 256;
    fill_kernel<<<eBlocks, 256, 0, stream>>>(src, dst, cursor, pbuf, E);

    // ---- Layers ----
    int gatherBlocks = (N * 32 + 255) / 256;
    int gemmBlocks = (N + 63) / 64;
    float invN = 1.0f / (float)N;
    const float* xin = x;
    for (int l = 0; l < L; ++l) {
        float* xout = (float*)d_out;  // layer0 intermediate lives in d_out, overwritten by layer1
        gather_kernel<<<gatherBlocks, 256, 0, stream>>>(xin, ea, rowptr, pbuf, aggx, sums, N);
        gemm_kernel<1><<<gemmBlocks, 256, 0, stream>>>(aggx, W1 + (size_t)l * 16384,
                                                       b1 + (size_t)l * 128, sums,
                                                       nullptr, nullptr, h, N, invN);
        gemm_kernel<2><<<gemmBlocks, 256, 0, stream>>>(h, W2 + (size_t)l * 16384,
                                                       b2 + (size_t)l * 128, sums,
                                                       gamma + (size_t)l * 128,
                                                       beta + (size_t)l * 128, xout, N, invN);
        xin = xout;
    }
}